// Round 12
// baseline (192.477 us; speedup 1.0000x reference)
//
#include <hip/hip_runtime.h>
#include <cstdint>
#include <cstddef>

typedef __bf16 bf16;
typedef __attribute__((ext_vector_type(8))) __bf16 bf16x8;
typedef __attribute__((ext_vector_type(4))) __bf16 bf16x4v;
typedef __attribute__((ext_vector_type(4))) float f32x4;
typedef __attribute__((ext_vector_type(16))) float f32x16;
typedef __attribute__((ext_vector_type(4))) short short4v;

#define T_N   2048
#define HID_N 2048
#define NH    16
#define NKV   8
#define HD    128

#define MFMA(a, b, c)   __builtin_amdgcn_mfma_f32_16x16x32_bf16((a), (b), (c), 0, 0, 0)
#define MFMA32(a, b, c) __builtin_amdgcn_mfma_f32_32x32x16_bf16((a), (b), (c), 0, 0, 0)

__device__ __forceinline__ f32x4 MFMA16(short4v a, short4v b, f32x4 c) {
#if __has_builtin(__builtin_amdgcn_mfma_f32_16x16x16bf16_1k)
    return __builtin_amdgcn_mfma_f32_16x16x16bf16_1k(a, b, c, 0, 0, 0);
#else
    asm volatile("v_mfma_f32_16x16x16_bf16 %0, %1, %2, %0\n\ts_nop 7\n\ts_nop 7"
                 : "+v"(c) : "v"(a), "v"(b));
    return c;
#endif
}

__device__ __forceinline__ void gl_lds16(const void* g, void* l) {
    __builtin_amdgcn_global_load_lds(
        (const __attribute__((address_space(1))) unsigned int*)g,
        (__attribute__((address_space(3))) unsigned int*)l,
        16, 0, 0);
}

__device__ __forceinline__ uint32_t pk2(float a, float b) {
    union { bf16 h; unsigned short u; } ca, cb;
    ca.h = (bf16)a; cb.h = (bf16)b;
    return ((uint32_t)cb.u << 16) | ca.u;
}

// heavy-first (ci,qt) <-> y mapping (flash kv-split). Inverse used by k_comb.
__device__ __forceinline__ void y2cq(int y, int& ci, int& qt) {
    if (y < 25)       { ci = 0; qt = y + 7; }
    else if (y < 42)  { ci = 1; qt = y - 10; }
    else if (y < 51)  { ci = 2; qt = y - 19; }
    else if (y == 51) { ci = 3; qt = 31; }
    else { int z = y - 52; int k = 7 - (z >> 2); ci = z & 3; qt = 8 * ci + k - 1; }
}
__device__ __forceinline__ int yof(int ci, int qt) {
    int k = qt + 1 - 8 * ci;
    if (k >= 8) {
        if (ci == 0) return qt - 7;
        if (ci == 1) return qt + 10;
        if (ci == 2) return qt + 19;
        return 51;
    }
    return 52 + (7 - k) * 4 + ci;
}

// ---------------- pre: weight converts + hidden RMSNorm (one launch) ----------
__global__ __launch_bounds__(256) void k_pre(const float* __restrict__ qkvw,
                                             bf16* __restrict__ qkvw_b,
                                             const float* __restrict__ ow,
                                             bf16* __restrict__ ow_b,
                                             const float* __restrict__ hid,
                                             const float* __restrict__ lw,
                                             bf16* __restrict__ normed) {
    const int blk = blockIdx.x, tid = threadIdx.x;
    if (blk < 6144) {
        const float* src; bf16* dst;
        if (blk < 4096) { int i = blk * 2048 + tid * 8; src = qkvw + i; dst = qkvw_b + i; }
        else            { int i = (blk - 4096) * 2048 + tid * 8; src = ow + i; dst = ow_b + i; }
        float4 x = ((const float4*)src)[0], y = ((const float4*)src)[1];
        bf16x8 v;
        v[0] = (bf16)x.x; v[1] = (bf16)x.y; v[2] = (bf16)x.z; v[3] = (bf16)x.w;
        v[4] = (bf16)y.x; v[5] = (bf16)y.y; v[6] = (bf16)y.z; v[7] = (bf16)y.w;
        *(bf16x8*)dst = v;
        return;
    }
    const int row = blk - 6144;
    const float* xr = hid + (size_t)row * HID_N;
    float4 a = ((const float4*)xr)[tid * 2];
    float4 b = ((const float4*)xr)[tid * 2 + 1];
    float ss = a.x*a.x + a.y*a.y + a.z*a.z + a.w*a.w
             + b.x*b.x + b.y*b.y + b.z*b.z + b.w*b.w;
    #pragma unroll
    for (int m = 32; m; m >>= 1) ss += __shfl_xor(ss, m);
    __shared__ float red[4];
    if ((tid & 63) == 0) red[tid >> 6] = ss;
    __syncthreads();
    float tot = red[0] + red[1] + red[2] + red[3];
    float rs = rsqrtf(tot * (1.0f / HID_N) + 1e-6f);
    const float4* wr = (const float4*)(lw + tid * 8);
    float4 wa = wr[0], wb = wr[1];
    bf16x8 v;
    v[0] = (bf16)(a.x * rs * wa.x); v[1] = (bf16)(a.y * rs * wa.y);
    v[2] = (bf16)(a.z * rs * wa.z); v[3] = (bf16)(a.w * rs * wa.w);
    v[4] = (bf16)(b.x * rs * wb.x); v[5] = (bf16)(b.y * rs * wb.y);
    v[6] = (bf16)(b.z * rs * wb.z); v[7] = (bf16)(b.w * rs * wb.w);
    *(bf16x8*)(normed + (size_t)row * HID_N + tid * 8) = v;
}

// ---------------- QKV GEMM: 64x128 tile, 32x32x16, 2-phase pipeline -----------
// grid (32,32) = 1024 blocks. bf16 out: cols [0,3072)->qkv3, [3072,4096)->vb.
// n-major XCD mapping: each XCD owns 4 n-panels (L2-resident B).
__global__ __launch_bounds__(256, 3) void k_gemm_qkv64(const bf16* __restrict__ A,
                                                       const bf16* __restrict__ B,
                                                       bf16* __restrict__ qkv3,
                                                       bf16* __restrict__ vb) {
    const int K = HID_N;
    __shared__ __attribute__((aligned(16))) bf16 As[2][64 * 64];    // 16 KB
    __shared__ __attribute__((aligned(16))) bf16 Bs[2][128 * 64];   // 32 KB
    const int tid = threadIdx.x;
    const int lane = tid & 63, wid = tid >> 6;
    const int col31 = lane & 31, khalf = lane >> 5;
    const int orig = blockIdx.y * gridDim.x + blockIdx.x;
    const int wgid = (orig & 7) * 128 + (orig >> 3);     // bijective, nwg=1024
    const size_t bm = (size_t)(wgid & 31) * 64, bn = (size_t)(wgid >> 5) * 128;

    f32x16 acc[2] = {};
    const int srow = tid >> 3;
    const int schk = tid & 7;

    // prologue: stage tile 0 into buffer 0
    #pragma unroll
    for (int c = 0; c < 2; c++) {
        int row = c * 32 + srow;
        int ka = (schk ^ (row & 7)) << 3;
        gl_lds16(A + (bm + row) * (size_t)K + ka, (char*)&As[0][0] + c * 4096 + tid * 16);
    }
    #pragma unroll
    for (int c = 0; c < 4; c++) {
        int row = c * 32 + srow;
        int ka = (schk ^ (row & 7)) << 3;
        gl_lds16(B + (bn + row) * (size_t)K + ka, (char*)&Bs[0][0] + c * 4096 + tid * 16);
    }
    asm volatile("s_waitcnt vmcnt(0) lgkmcnt(0)" ::: "memory");
    __builtin_amdgcn_s_barrier();

    for (int k0 = 0; k0 < K; k0 += 64) {
        const int cur = (k0 >> 6) & 1;
        if (k0 + 64 < K) {
            const int kn = k0 + 64;
            #pragma unroll
            for (int c = 0; c < 2; c++) {
                int row = c * 32 + srow;
                int ka = (schk ^ (row & 7)) << 3;
                gl_lds16(A + (bm + row) * (size_t)K + kn + ka,
                         (char*)&As[cur ^ 1][0] + c * 4096 + tid * 16);
            }
            #pragma unroll
            for (int c = 0; c < 4; c++) {
                int row = c * 32 + srow;
                int ka = (schk ^ (row & 7)) << 3;
                gl_lds16(B + (bn + row) * (size_t)K + kn + ka,
                         (char*)&Bs[cur ^ 1][0] + c * 4096 + tid * 16);
            }
        }
        const bf16* Ab = &As[cur][0];
        const bf16* Bb = &Bs[cur][0];
        __builtin_amdgcn_s_setprio(1);
        #pragma unroll
        for (int kb2 = 0; kb2 < 4; kb2++) {
            bf16x8 af[2], bfr;
            #pragma unroll
            for (int mt = 0; mt < 2; mt++) {
                int row = mt * 32 + col31;
                af[mt] = *(const bf16x8*)(Ab + row * 64 + (((2 * kb2 + khalf) ^ (row & 7)) << 3));
            }
            {
                int row = wid * 32 + col31;
                bfr = *(const bf16x8*)(Bb + row * 64 + (((2 * kb2 + khalf) ^ (row & 7)) << 3));
            }
            #pragma unroll
            for (int mt = 0; mt < 2; mt++)
                acc[mt] = MFMA32(af[mt], bfr, acc[mt]);
        }
        __builtin_amdgcn_s_setprio(0);
        asm volatile("s_waitcnt vmcnt(0) lgkmcnt(0)" ::: "memory");
        __builtin_amdgcn_s_barrier();
    }
    #pragma unroll
    for (int mt = 0; mt < 2; mt++)
        #pragma unroll
        for (int i = 0; i < 16; i++) {
            int rowl = (i & 3) + 8 * (i >> 2) + 4 * khalf;
            size_t row = bm + mt * 32 + rowl;
            size_t col = bn + wid * 32 + col31;
            bf16 val = (bf16)acc[mt][i];
            if (col < 3072) qkv3[row * 3072 + col] = val;
            else            vb[row * 1024 + (col - 3072)] = val;
        }
}

// ---------------- O-proj GEMM: 64x128, 32x32x16, 2-phase pipeline -------------
__global__ __launch_bounds__(256, 3) void k_gemm_bt64(const bf16* __restrict__ A,
                                                      const bf16* __restrict__ B,
                                                      float* __restrict__ C,
                                                      int M, int N, int K) {
    __shared__ __attribute__((aligned(16))) bf16 As[2][64 * 64];    // 16 KB
    __shared__ __attribute__((aligned(16))) bf16 Bs[2][128 * 64];   // 32 KB
    const int tid = threadIdx.x;
    const int lane = tid & 63, wid = tid >> 6;
    const int col31 = lane & 31, khalf = lane >> 5;
    const int orig = blockIdx.y * gridDim.x + blockIdx.x;
    const int wgid = (orig & 7) * 64 + (orig >> 3);      // bijective, nwg=512
    const size_t bm = (size_t)(wgid & 31) * 64, bn = (size_t)(wgid >> 5) * 128;

    f32x16 acc[2] = {};
    const int srow = tid >> 3;
    const int schk = tid & 7;

    #pragma unroll
    for (int c = 0; c < 2; c++) {
        int row = c * 32 + srow;
        int ka = (schk ^ (row & 7)) << 3;
        gl_lds16(A + (bm + row) * (size_t)K + ka, (char*)&As[0][0] + c * 4096 + tid * 16);
    }
    #pragma unroll
    for (int c = 0; c < 4; c++) {
        int row = c * 32 + srow;
        int ka = (schk ^ (row & 7)) << 3;
        gl_lds16(B + (bn + row) * (size_t)K + ka, (char*)&Bs[0][0] + c * 4096 + tid * 16);
    }
    asm volatile("s_waitcnt vmcnt(0) lgkmcnt(0)" ::: "memory");
    __builtin_amdgcn_s_barrier();

    for (int k0 = 0; k0 < K; k0 += 64) {
        const int cur = (k0 >> 6) & 1;
        if (k0 + 64 < K) {
            const int kn = k0 + 64;
            #pragma unroll
            for (int c = 0; c < 2; c++) {
                int row = c * 32 + srow;
                int ka = (schk ^ (row & 7)) << 3;
                gl_lds16(A + (bm + row) * (size_t)K + kn + ka,
                         (char*)&As[cur ^ 1][0] + c * 4096 + tid * 16);
            }
            #pragma unroll
            for (int c = 0; c < 4; c++) {
                int row = c * 32 + srow;
                int ka = (schk ^ (row & 7)) << 3;
                gl_lds16(B + (bn + row) * (size_t)K + kn + ka,
                         (char*)&Bs[cur ^ 1][0] + c * 4096 + tid * 16);
            }
        }
        const bf16* Ab = &As[cur][0];
        const bf16* Bb = &Bs[cur][0];
        __builtin_amdgcn_s_setprio(1);
        #pragma unroll
        for (int kb2 = 0; kb2 < 4; kb2++) {
            bf16x8 af[2], bfr;
            #pragma unroll
            for (int mt = 0; mt < 2; mt++) {
                int row = mt * 32 + col31;
                af[mt] = *(const bf16x8*)(Ab + row * 64 + (((2 * kb2 + khalf) ^ (row & 7)) << 3));
            }
            {
                int row = wid * 32 + col31;
                bfr = *(const bf16x8*)(Bb + row * 64 + (((2 * kb2 + khalf) ^ (row & 7)) << 3));
            }
            #pragma unroll
            for (int mt = 0; mt < 2; mt++)
                acc[mt] = MFMA32(af[mt], bfr, acc[mt]);
        }
        __builtin_amdgcn_s_setprio(0);
        asm volatile("s_waitcnt vmcnt(0) lgkmcnt(0)" ::: "memory");
        __builtin_amdgcn_s_barrier();
    }
    #pragma unroll
    for (int mt = 0; mt < 2; mt++)
        #pragma unroll
        for (int i = 0; i < 16; i++) {
            int rowl = (i & 3) + 8 * (i >> 2) + 4 * khalf;
            size_t row = bm + mt * 32 + rowl;
            size_t col = bn + wid * 32 + col31;
            C[row * (size_t)N + col] = acc[mt][i];
        }
}

// ---------------- mid: per-head RMSNorm+RoPE (y<12) and V transpose (y==12) ---
__global__ __launch_bounds__(256) void k_mid(const bf16* __restrict__ qkv3,
                                             const float* __restrict__ qw,
                                             const float* __restrict__ kw,
                                             const int* __restrict__ pos,
                                             bf16* __restrict__ q,
                                             bf16* __restrict__ k,
                                             const bf16* __restrict__ vin,
                                             bf16* __restrict__ vT) {
    const int tid = threadIdx.x;
    if (blockIdx.y == 12) {
        const int bx = blockIdx.x;
        if (bx >= 512) return;
        __shared__ bf16 tile[64][72];
        const int tb = bx & 31, db = bx >> 5;
        const int row = tid >> 2, cc = tid & 3;
        const bf16* src = vin + (size_t)(tb * 64 + row) * 1024 + db * 64 + cc * 16;
        bf16x8 a = *(const bf16x8*)(src);
        bf16x8 b = *(const bf16x8*)(src + 8);
        #pragma unroll
        for (int i = 0; i < 8; i++) tile[row][cc * 16 + i] = a[i];
        #pragma unroll
        for (int i = 0; i < 8; i++) tile[row][cc * 16 + 8 + i] = b[i];
        __syncthreads();
        bf16* dst = vT + (size_t)(db * 64 + row) * 2048 + tb * 64 + cc * 16;
        bf16x8 o1, o2;
        #pragma unroll
        for (int i = 0; i < 8; i++) o1[i] = tile[cc * 16 + i][row];
        #pragma unroll
        for (int i = 0; i < 8; i++) o2[i] = tile[cc * 16 + 8 + i][row];
        *(bf16x8*)dst = o1;
        *(bf16x8*)(dst + 8) = o2;
        return;
    }
    const int t = blockIdx.x;
    const int half = tid >> 7, d = tid & 127;
    const int slot = blockIdx.y * 2 + half;
    const bool isq = slot < 16;
    const int h = isq ? slot : slot - 16;
    float x = (float)qkv3[(size_t)t * 3072 + slot * 128 + d];
    float ss = x * x;
    #pragma unroll
    for (int m = 32; m; m >>= 1) ss += __shfl_xor(ss, m);
    __shared__ float red[4];
    __shared__ float sh[256];
    if ((tid & 63) == 0) red[tid >> 6] = ss;
    __syncthreads();
    float rs = rsqrtf((red[half * 2] + red[half * 2 + 1]) * (1.0f / HD) + 1e-6f);
    float nx = x * rs * (isq ? qw[d] : kw[d]);
    sh[tid] = nx;
    __syncthreads();
    float other = sh[tid ^ 64];
    int j = d & 63;
    float ang = (float)pos[t] * __powf(10000.f, -(float)j * (1.f / 64.f));
    float s, c;
    __sincosf(ang, &s, &c);
    float o = (d < 64) ? (nx * c - other * s) : (nx * c + other * s);
    bf16* dst = isq ? (q + ((size_t)t * NH + h) * HD + d)
                    : (k + ((size_t)t * NKV + h) * HD + d);
    *dst = (bf16)o;
}

// ---------------- flash attention (R8-verified, unchanged) --------------------
__global__ __launch_bounds__(256, 3) void k_flash(const bf16* __restrict__ Q,
                                                  const bf16* __restrict__ K,
                                                  const bf16* __restrict__ VT,
                                                  bf16* __restrict__ On,
                                                  float* __restrict__ ml) {
    __shared__ __attribute__((aligned(16))) bf16 Ks2[2][64 * 128];  // 32 KB
    __shared__ __attribute__((aligned(16))) bf16 Vt[128 * 64];      // 16 KB

    const int tid = threadIdx.x, lane = tid & 63, w = tid >> 6;
    const int r = lane & 15, g = lane >> 4;
    const int h = blockIdx.x, y = blockIdx.y;
    int ci, qt;
    y2cq(y, ci, qt);
    const int c0 = ci * 8;
    const int ntl = min(qt + 1 - c0, 8);
    const int q0 = qt * 64;
    const int gh = h >> 1;
    const int q0w = q0 + w * 16;

    const int rowk = tid >> 4, posc = tid & 15;
    const int vrow = tid >> 3, vkb = tid & 7;
    const bf16* VTh = VT + (size_t)gh * 128 * 2048;

    bf16x8 qf[4];
    #pragma unroll
    for (int ks = 0; ks < 4; ks++)
        qf[ks] = *(const bf16x8*)(Q + ((size_t)(q0w + r) * NH + h) * HD + ks * 32 + g * 8);

    f32x4 acc[8] = {};
    float m_run = -1e30f, l_run = 0.f;
    const float scale = 0.08838834764831845f;

    {
        const int kv0 = c0 * 64;
        #pragma unroll
        for (int c = 0; c < 4; c++) {
            int row = c * 16 + rowk;
            int srcc = posc ^ (row & 7);
            gl_lds16(K + ((size_t)(kv0 + row) * NKV + gh) * HD + srcc * 8,
                     (char*)&Ks2[0][0] + c * 4096 + tid * 16);
        }
        asm volatile("s_waitcnt vmcnt(0)" ::: "memory");
        __builtin_amdgcn_s_barrier();
    }

    for (int t = 0; t < ntl; ++t) {
        const int b = t & 1;
        const int kv0 = (c0 + t) * 64;
        const bool pf = (t + 1 < ntl);
        #pragma unroll
        for (int it = 0; it < 4; it++) {
            int d = it * 32 + vrow;
            int srck = (vkb ^ (vrow & 7)) * 8;
            gl_lds16(VTh + (size_t)d * 2048 + kv0 + srck,
                     (char*)&Vt[0] + it * 4096 + tid * 16);
        }
        if (pf) {
            const int kv1 = kv0 + 64;
            #pragma unroll
            for (int c = 0; c < 4; c++) {
                int row = c * 16 + rowk;
                int srcc = posc ^ (row & 7);
                gl_lds16(K + ((size_t)(kv1 + row) * NKV + gh) * HD + srcc * 8,
                         (char*)&Ks2[0][0] + (b ^ 1) * 16384 + c * 4096 + tid * 16);
            }
        }
        const bool compute = (kv0 <= q0w + 15);
        union PB { uint32_t u[2]; short4v s; };
        PB pbu[4];
        if (compute) {
            const bf16* Kb = &Ks2[b][0];
            const bool fullt = (kv0 + 63 <= q0w);
            float sc[4][4];
            __builtin_amdgcn_s_setprio(1);
            #pragma unroll
            for (int t4 = 0; t4 < 4; t4++) {
                f32x4 S = {};
                #pragma unroll
                for (int ks = 0; ks < 4; ks++) {
                    int row = t4 * 16 + r;
                    bf16x8 kf = *(const bf16x8*)(Kb + row * 128 + (((4 * ks + g) ^ (row & 7)) * 8));
                    S = MFMA(kf, qf[ks], S);
                }
                if (fullt) {
                    #pragma unroll
                    for (int j = 0; j < 4; j++) sc[t4][j] = S[j] * scale;
                } else {
                    #pragma unroll
                    for (int j = 0; j < 4; j++) {
                        int kg = kv0 + t4 * 16 + 4 * g + j;
                        sc[t4][j] = (kg <= q0w + r) ? S[j] * scale : -1e30f;
                    }
                }
            }
            __builtin_amdgcn_s_setprio(0);
            float mx = sc[0][0];
            #pragma unroll
            for (int t4 = 0; t4 < 4; t4++)
                #pragma unroll
                for (int j = 0; j < 4; j++) mx = fmaxf(mx, sc[t4][j]);
            mx = fmaxf(mx, __shfl_xor(mx, 16));
            mx = fmaxf(mx, __shfl_xor(mx, 32));
            const bool nr = __all(mx <= m_run + 8.0f) != 0;
            float mn, alpha;
            if (nr) { mn = m_run; alpha = 1.0f; }
            else    { mn = fmaxf(m_run, mx); alpha = __expf(m_run - mn); m_run = mn; }
            float rsum = 0.f;
            #pragma unroll
            for (int t4 = 0; t4 < 4; t4++)
                #pragma unroll
                for (int j = 0; j < 4; j++) {
                    sc[t4][j] = __expf(sc[t4][j] - mn);
                    rsum += sc[t4][j];
                }
            rsum += __shfl_xor(rsum, 16);
            rsum += __shfl_xor(rsum, 32);
            l_run = l_run * alpha + rsum;
            if (!nr) {
                #pragma unroll
                for (int f = 0; f < 8; f++)
                    #pragma unroll
                    for (int j = 0; j < 4; j++) acc[f][j] *= alpha;
            }
            #pragma unroll
            for (int t4 = 0; t4 < 4; t4++) {
                pbu[t4].u[0] = pk2(sc[t4][0], sc[t4][1]);
                pbu[t4].u[1] = pk2(sc[t4][2], sc[t4][3]);
            }
        }
        if (pf) asm volatile("s_waitcnt vmcnt(4)" ::: "memory");
        else    asm volatile("s_waitcnt vmcnt(0)" ::: "memory");
        __builtin_amdgcn_s_barrier();
        if (compute) {
            const char* Vb = (const char*)&Vt[0];
            __builtin_amdgcn_s_setprio(1);
            #pragma unroll
            for (int f = 0; f < 8; f++) {
                #pragma unroll
                for (int t4 = 0; t4 < 4; t4++) {
                    short4v vf = *(const short4v*)(Vb + f * 2048 + r * 128 +
                                  (((2 * t4 + (g >> 1)) ^ (r & 7)) * 16) + (g & 1) * 8);
                    acc[f] = MFMA16(vf, pbu[t4].s, acc[f]);
                }
            }
            __builtin_amdgcn_s_setprio(0);
        }
        asm volatile("s_waitcnt vmcnt(0)" ::: "memory");
        __builtin_amdgcn_s_barrier();
    }
    const int lr = w * 16 + r;
    float inv_l = 1.0f / l_run;
    bf16* Ob = On + ((size_t)(h * 80 + y)) * 8192 + lr * 128;
    #pragma unroll
    for (int f = 0; f < 8; f++) {
        bf16x4v ov;
        #pragma unroll
        for (int j = 0; j < 4; j++) ov[j] = (bf16)(acc[f][j] * inv_l);
        *(bf16x4v*)(Ob + f * 16 + 4 * g) = ov;
    }
    if (g == 0) {
        float* mlp = ml + ((size_t)(h * 80 + y)) * 128;
        mlp[lr] = m_run;
        mlp[64 + lr] = l_run;
    }
}

// ---------------- combine partials (coalesced) ----------------
__global__ __launch_bounds__(256) void k_comb(const bf16* __restrict__ On,
                                              const float* __restrict__ ml,
                                              bf16* __restrict__ ao) {
    const int h = blockIdx.x, qt = blockIdx.y;
    const int tid = threadIdx.x;
    const int dc = tid & 15;
    const int qr = tid >> 4;
    const int nc = 1 + (qt >= 8) + (qt >= 16) + (qt >= 24);
    int ys[4];
    #pragma unroll
    for (int i = 0; i < 4; i++) ys[i] = (i < nc) ? yof(i, qt) : 0;
    #pragma unroll
    for (int p = 0; p < 4; p++) {
        const int lq = p * 16 + qr;
        float mi[4], li[4], wi[4];
        float mstar = -1e30f;
        for (int i = 0; i < 4; i++) {
            if (i < nc) {
                const float* pml = ml + ((size_t)(h * 80 + ys[i])) * 128;
                mi[i] = pml[lq]; li[i] = pml[64 + lq];
                mstar = fmaxf(mstar, mi[i]);
            }
        }
        float wsum = 0.f;
        for (int i = 0; i < 4; i++) {
            if (i < nc) { wi[i] = li[i] * __expf(mi[i] - mstar); wsum += wi[i]; }
            else wi[i] = 0.f;
        }
        float inv = 1.f / wsum;
        float o[8] = {};
        for (int i = 0; i < 4; i++) {
            if (i < nc) {
                bf16x8 v = *(const bf16x8*)(On + ((size_t)(h * 80 + ys[i])) * 8192 +
                                            lq * 128 + dc * 8);
                float wn = wi[i] * inv;
                #pragma unroll
                for (int j = 0; j < 8; j++) o[j] += wn * (float)v[j];
            }
        }
        bf16x8 ov;
        #pragma unroll
        for (int j = 0; j < 8; j++) ov[j] = (bf16)o[j];
        const int q = qt * 64 + lq;
        *(bf16x8*)(ao + ((size_t)q * NH + h) * HD + dc * 8) = ov;
    }
}

// ---------------- launch ----------------
extern "C" void kernel_launch(void* const* d_in, const int* in_sizes, int n_in,
                              void* d_out, int out_size, void* d_ws, size_t ws_size,
                              hipStream_t stream) {
    const int*   pos  = (const int*)d_in[0];
    const float* hid  = (const float*)d_in[1];
    const float* lw   = (const float*)d_in[2];
    const float* qkvw = (const float*)d_in[3];
    const float* qnw  = (const float*)d_in[4];
    const float* knw  = (const float*)d_in[5];
    const float* ow   = (const float*)d_in[6];
    float* out = (float*)d_out;

    char* ws = (char*)d_ws;
    bf16*  qkvw_b = (bf16*)(ws);                   // 0..16 MB
    bf16*  ow_b   = (bf16*)(ws + (16u << 20));     // 16..24 MB
    bf16*  normed = (bf16*)(ws + (24u << 20));     // 24..32 MB (reused as ao)
    bf16*  qkv3   = (bf16*)(ws + (32u << 20));     // 32..44.6 MB (dead after k_mid)
    bf16*  qb     = (bf16*)(ws + (64u << 20));     // 64..72 MB
    bf16*  kb     = (bf16*)(ws + (72u << 20));     // 72..76 MB
    bf16*  vb     = (bf16*)(ws + (76u << 20));     // 76..80 MB
    bf16*  ao     = normed;
    bf16*  On     = (bf16*)(ws + (32u << 20));     // reuses qkv3 region (21 MB)
    float* ml     = (float*)(ws + (54u << 20));    // 54..54.7 MB
    bf16*  vT     = (bf16*)(ws + (56u << 20));     // 56..60 MB (transposed V)

    k_pre<<<8192, 256, 0, stream>>>(qkvw, qkvw_b, ow, ow_b, hid, lw, normed);
    k_gemm_qkv64<<<dim3(32, 32), 256, 0, stream>>>(normed, qkvw_b, qkv3, vb);
    k_mid<<<dim3(T_N, 13), 256, 0, stream>>>(qkv3, qnw, knw, pos, qb, kb, vb, vT);
    k_flash<<<dim3(NH, 80), 256, 0, stream>>>(qb, kb, vT, On, ml);
    k_comb<<<dim3(NH, 32), 256, 0, stream>>>(On, ml, ao);
    k_gemm_bt64<<<dim3(16, 32), 256, 0, stream>>>(ao, ow_b, out, 2048, 2048, 2048);
}

// Round 13
// 168.507 us; speedup vs baseline: 1.1422x; 1.1422x over previous
//
#include <hip/hip_runtime.h>
#include <cstdint>
#include <cstddef>

typedef __bf16 bf16;
typedef __attribute__((ext_vector_type(8))) __bf16 bf16x8;
typedef __attribute__((ext_vector_type(4))) __bf16 bf16x4v;
typedef __attribute__((ext_vector_type(4))) float f32x4;
typedef __attribute__((ext_vector_type(16))) float f32x16;
typedef __attribute__((ext_vector_type(4))) short short4v;

#define T_N   2048
#define HID_N 2048
#define NH    16
#define NKV   8
#define HD    128

#define MFMA(a, b, c)   __builtin_amdgcn_mfma_f32_16x16x32_bf16((a), (b), (c), 0, 0, 0)
#define MFMA32(a, b, c) __builtin_amdgcn_mfma_f32_32x32x16_bf16((a), (b), (c), 0, 0, 0)

__device__ __forceinline__ f32x4 MFMA16(short4v a, short4v b, f32x4 c) {
#if __has_builtin(__builtin_amdgcn_mfma_f32_16x16x16bf16_1k)
    return __builtin_amdgcn_mfma_f32_16x16x16bf16_1k(a, b, c, 0, 0, 0);
#else
    asm volatile("v_mfma_f32_16x16x16_bf16 %0, %1, %2, %0\n\ts_nop 7\n\ts_nop 7"
                 : "+v"(c) : "v"(a), "v"(b));
    return c;
#endif
}

__device__ __forceinline__ void gl_lds16(const void* g, void* l) {
    __builtin_amdgcn_global_load_lds(
        (const __attribute__((address_space(1))) unsigned int*)g,
        (__attribute__((address_space(3))) unsigned int*)l,
        16, 0, 0);
}

__device__ __forceinline__ uint32_t pk2(float a, float b) {
    union { bf16 h; unsigned short u; } ca, cb;
    ca.h = (bf16)a; cb.h = (bf16)b;
    return ((uint32_t)cb.u << 16) | ca.u;
}

// heavy-first (ci,qt) <-> y mapping (flash kv-split). Inverse used by k_comb.
__device__ __forceinline__ void y2cq(int y, int& ci, int& qt) {
    if (y < 25)       { ci = 0; qt = y + 7; }
    else if (y < 42)  { ci = 1; qt = y - 10; }
    else if (y < 51)  { ci = 2; qt = y - 19; }
    else if (y == 51) { ci = 3; qt = 31; }
    else { int z = y - 52; int k = 7 - (z >> 2); ci = z & 3; qt = 8 * ci + k - 1; }
}
__device__ __forceinline__ int yof(int ci, int qt) {
    int k = qt + 1 - 8 * ci;
    if (k >= 8) {
        if (ci == 0) return qt - 7;
        if (ci == 1) return qt + 10;
        if (ci == 2) return qt + 19;
        return 51;
    }
    return 52 + (7 - k) * 4 + ci;
}

// ---------------- pre: weight converts + hidden RMSNorm + RoPE table ----------
// blocks [0,6144): fp32->bf16 converts; [6144,8192): RMSNorm rows;
// [8192,8704): rope table rope[t][j] = {cos,sin}(pos[t] * theta^-j/64).
__global__ __launch_bounds__(256) void k_pre(const float* __restrict__ qkvw,
                                             bf16* __restrict__ qkvw_b,
                                             const float* __restrict__ ow,
                                             bf16* __restrict__ ow_b,
                                             const float* __restrict__ hid,
                                             const float* __restrict__ lw,
                                             bf16* __restrict__ normed,
                                             const int* __restrict__ pos,
                                             float2* __restrict__ rope) {
    const int blk = blockIdx.x, tid = threadIdx.x;
    if (blk < 6144) {
        const float* src; bf16* dst;
        if (blk < 4096) { int i = blk * 2048 + tid * 8; src = qkvw + i; dst = qkvw_b + i; }
        else            { int i = (blk - 4096) * 2048 + tid * 8; src = ow + i; dst = ow_b + i; }
        float4 x = ((const float4*)src)[0], y = ((const float4*)src)[1];
        bf16x8 v;
        v[0] = (bf16)x.x; v[1] = (bf16)x.y; v[2] = (bf16)x.z; v[3] = (bf16)x.w;
        v[4] = (bf16)y.x; v[5] = (bf16)y.y; v[6] = (bf16)y.z; v[7] = (bf16)y.w;
        *(bf16x8*)dst = v;
        return;
    }
    if (blk >= 8192) {
        const int t = (blk - 8192) * 4 + (tid >> 6);
        const int j = tid & 63;
        float ang = (float)pos[t] * __powf(10000.f, -(float)j * (1.f / 64.f));
        float s, c;
        __sincosf(ang, &s, &c);
        rope[t * 64 + j] = make_float2(c, s);
        return;
    }
    const int row = blk - 6144;
    const float* xr = hid + (size_t)row * HID_N;
    float4 a = ((const float4*)xr)[tid * 2];
    float4 b = ((const float4*)xr)[tid * 2 + 1];
    float ss = a.x*a.x + a.y*a.y + a.z*a.z + a.w*a.w
             + b.x*b.x + b.y*b.y + b.z*b.z + b.w*b.w;
    #pragma unroll
    for (int m = 32; m; m >>= 1) ss += __shfl_xor(ss, m);
    __shared__ float red[4];
    if ((tid & 63) == 0) red[tid >> 6] = ss;
    __syncthreads();
    float tot = red[0] + red[1] + red[2] + red[3];
    float rs = rsqrtf(tot * (1.0f / HID_N) + 1e-6f);
    const float4* wr = (const float4*)(lw + tid * 8);
    float4 wa = wr[0], wb = wr[1];
    bf16x8 v;
    v[0] = (bf16)(a.x * rs * wa.x); v[1] = (bf16)(a.y * rs * wa.y);
    v[2] = (bf16)(a.z * rs * wa.z); v[3] = (bf16)(a.w * rs * wa.w);
    v[4] = (bf16)(b.x * rs * wb.x); v[5] = (bf16)(b.y * rs * wb.y);
    v[6] = (bf16)(b.z * rs * wb.z); v[7] = (bf16)(b.w * rs * wb.w);
    *(bf16x8*)(normed + (size_t)row * HID_N + tid * 8) = v;
}

// ---------------- QKV GEMM: 128x128, 32x32x16 MFMA (R10-verified) -------------
__global__ __launch_bounds__(256, 3) void k_gemm_qkv(const bf16* __restrict__ A,
                                                     const bf16* __restrict__ B,
                                                     bf16* __restrict__ qkv3,
                                                     bf16* __restrict__ vb) {
    const int K = HID_N;
    __shared__ __attribute__((aligned(16))) bf16 As[128 * 64];
    __shared__ __attribute__((aligned(16))) bf16 Bs[128 * 64];
    const int tid = threadIdx.x;
    const int lane = tid & 63, wid = tid >> 6;
    const int wm = wid >> 1, wn = wid & 1;
    const int col31 = lane & 31, khalf = lane >> 5;
    const int orig = blockIdx.y * gridDim.x + blockIdx.x;
    const int wgid = (orig & 7) * 64 + (orig >> 3);
    const size_t bm = (size_t)(wgid >> 5) * 128, bn = (size_t)(wgid & 31) * 128;

    f32x16 acc[2][2] = {};
    const int srow = tid >> 3;
    const int schk = tid & 7;

    for (int k0 = 0; k0 < K; k0 += 64) {
        __syncthreads();
        #pragma unroll
        for (int c = 0; c < 4; c++) {
            int row = c * 32 + srow;
            int ka = (schk ^ (row & 7)) << 3;
            gl_lds16(A + (bm + row) * (size_t)K + k0 + ka,
                     (char*)As + c * 4096 + tid * 16);
            gl_lds16(B + (bn + row) * (size_t)K + k0 + ka,
                     (char*)Bs + c * 4096 + tid * 16);
        }
        __syncthreads();
        #pragma unroll
        for (int kb = 0; kb < 4; kb++) {
            bf16x8 af[2], bfr[2];
            #pragma unroll
            for (int mt = 0; mt < 2; mt++) {
                int row = wm * 64 + mt * 32 + col31;
                af[mt] = *(const bf16x8*)(As + row * 64 + (((2 * kb + khalf) ^ (row & 7)) << 3));
            }
            #pragma unroll
            for (int nt = 0; nt < 2; nt++) {
                int row = wn * 64 + nt * 32 + col31;
                bfr[nt] = *(const bf16x8*)(Bs + row * 64 + (((2 * kb + khalf) ^ (row & 7)) << 3));
            }
            #pragma unroll
            for (int mt = 0; mt < 2; mt++)
                #pragma unroll
                for (int nt = 0; nt < 2; nt++)
                    acc[mt][nt] = MFMA32(af[mt], bfr[nt], acc[mt][nt]);
        }
    }
    #pragma unroll
    for (int mt = 0; mt < 2; mt++)
        #pragma unroll
        for (int nt = 0; nt < 2; nt++)
            #pragma unroll
            for (int i = 0; i < 16; i++) {
                int rowl = (i & 3) + 8 * (i >> 2) + 4 * khalf;
                size_t row = bm + wm * 64 + mt * 32 + rowl;
                size_t col = bn + wn * 64 + nt * 32 + col31;
                bf16 val = (bf16)acc[mt][nt][i];
                if (col < 3072) qkv3[row * 3072 + col] = val;
                else            vb[row * 1024 + (col - 3072)] = val;
            }
}

// ---------------- O-proj GEMM: 64x128 tile, 32x32x16 (R10-verified) ----------
__global__ __launch_bounds__(256, 3) void k_gemm_bt64(const bf16* __restrict__ A,
                                                      const bf16* __restrict__ B,
                                                      float* __restrict__ C,
                                                      int M, int N, int K) {
    __shared__ __attribute__((aligned(16))) bf16 As[64 * 64];    // 8 KB
    __shared__ __attribute__((aligned(16))) bf16 Bs[128 * 64];   // 16 KB
    const int tid = threadIdx.x;
    const int lane = tid & 63, wid = tid >> 6;
    const int col31 = lane & 31, khalf = lane >> 5;
    const int orig = blockIdx.y * gridDim.x + blockIdx.x;
    const int wgid = (orig & 7) * 64 + (orig >> 3);
    const size_t bm = (size_t)(wgid >> 4) * 64, bn = (size_t)(wgid & 15) * 128;

    f32x16 acc[2] = {};
    const int srow = tid >> 3;
    const int schk = tid & 7;

    for (int k0 = 0; k0 < K; k0 += 64) {
        __syncthreads();
        #pragma unroll
        for (int c = 0; c < 2; c++) {
            int row = c * 32 + srow;
            int ka = (schk ^ (row & 7)) << 3;
            gl_lds16(A + (bm + row) * (size_t)K + k0 + ka,
                     (char*)As + c * 4096 + tid * 16);
        }
        #pragma unroll
        for (int c = 0; c < 4; c++) {
            int row = c * 32 + srow;
            int ka = (schk ^ (row & 7)) << 3;
            gl_lds16(B + (bn + row) * (size_t)K + k0 + ka,
                     (char*)Bs + c * 4096 + tid * 16);
        }
        __syncthreads();
        #pragma unroll
        for (int kb = 0; kb < 4; kb++) {
            bf16x8 af[2], bfr;
            #pragma unroll
            for (int mt = 0; mt < 2; mt++) {
                int row = mt * 32 + col31;
                af[mt] = *(const bf16x8*)(As + row * 64 + (((2 * kb + khalf) ^ (row & 7)) << 3));
            }
            {
                int row = wid * 32 + col31;
                bfr = *(const bf16x8*)(Bs + row * 64 + (((2 * kb + khalf) ^ (row & 7)) << 3));
            }
            #pragma unroll
            for (int mt = 0; mt < 2; mt++)
                acc[mt] = MFMA32(af[mt], bfr, acc[mt]);
        }
    }
    #pragma unroll
    for (int mt = 0; mt < 2; mt++)
        #pragma unroll
        for (int i = 0; i < 16; i++) {
            int rowl = (i & 3) + 8 * (i >> 2) + 4 * khalf;
            size_t row = bm + mt * 32 + rowl;
            size_t col = bn + wid * 32 + col31;
            C[row * (size_t)N + col] = acc[mt][i];
        }
}

// ---------------- mid: per-head RMSNorm+RoPE (table) and V transpose ----------
__global__ __launch_bounds__(256) void k_mid(const bf16* __restrict__ qkv3,
                                             const float* __restrict__ qw,
                                             const float* __restrict__ kw,
                                             const float2* __restrict__ rope,
                                             bf16* __restrict__ q,
                                             bf16* __restrict__ k,
                                             const bf16* __restrict__ vin,
                                             bf16* __restrict__ vT) {
    const int tid = threadIdx.x;
    if (blockIdx.y == 12) {
        const int bx = blockIdx.x;
        if (bx >= 512) return;
        __shared__ bf16 tile[64][72];
        const int tb = bx & 31, db = bx >> 5;
        const int row = tid >> 2, cc = tid & 3;
        const bf16* src = vin + (size_t)(tb * 64 + row) * 1024 + db * 64 + cc * 16;
        bf16x8 a = *(const bf16x8*)(src);
        bf16x8 b = *(const bf16x8*)(src + 8);
        #pragma unroll
        for (int i = 0; i < 8; i++) tile[row][cc * 16 + i] = a[i];
        #pragma unroll
        for (int i = 0; i < 8; i++) tile[row][cc * 16 + 8 + i] = b[i];
        __syncthreads();
        bf16* dst = vT + (size_t)(db * 64 + row) * 2048 + tb * 64 + cc * 16;
        bf16x8 o1, o2;
        #pragma unroll
        for (int i = 0; i < 8; i++) o1[i] = tile[cc * 16 + i][row];
        #pragma unroll
        for (int i = 0; i < 8; i++) o2[i] = tile[cc * 16 + 8 + i][row];
        *(bf16x8*)dst = o1;
        *(bf16x8*)(dst + 8) = o2;
        return;
    }
    const int t = blockIdx.x;
    const int half = tid >> 7, d = tid & 127;
    const int slot = blockIdx.y * 2 + half;
    const bool isq = slot < 16;
    const int h = isq ? slot : slot - 16;
    float x = (float)qkv3[(size_t)t * 3072 + slot * 128 + d];
    float ss = x * x;
    #pragma unroll
    for (int m = 32; m; m >>= 1) ss += __shfl_xor(ss, m);
    __shared__ float red[4];
    __shared__ float sh[256];
    if ((tid & 63) == 0) red[tid >> 6] = ss;
    __syncthreads();
    float rs = rsqrtf((red[half * 2] + red[half * 2 + 1]) * (1.0f / HD) + 1e-6f);
    float nx = x * rs * (isq ? qw[d] : kw[d]);
    sh[tid] = nx;
    __syncthreads();
    float other = sh[tid ^ 64];
    float2 cs = rope[t * 64 + (d & 63)];
    float o = (d < 64) ? (nx * cs.x - other * cs.y) : (nx * cs.x + other * cs.y);
    bf16* dst = isq ? (q + ((size_t)t * NH + h) * HD + d)
                    : (k + ((size_t)t * NKV + h) * HD + d);
    *dst = (bf16)o;
}

// ---------------- flash attention (R8-verified, unchanged) --------------------
__global__ __launch_bounds__(256, 3) void k_flash(const bf16* __restrict__ Q,
                                                  const bf16* __restrict__ K,
                                                  const bf16* __restrict__ VT,
                                                  bf16* __restrict__ On,
                                                  float* __restrict__ ml) {
    __shared__ __attribute__((aligned(16))) bf16 Ks2[2][64 * 128];  // 32 KB
    __shared__ __attribute__((aligned(16))) bf16 Vt[128 * 64];      // 16 KB

    const int tid = threadIdx.x, lane = tid & 63, w = tid >> 6;
    const int r = lane & 15, g = lane >> 4;
    const int h = blockIdx.x, y = blockIdx.y;
    int ci, qt;
    y2cq(y, ci, qt);
    const int c0 = ci * 8;
    const int ntl = min(qt + 1 - c0, 8);
    const int q0 = qt * 64;
    const int gh = h >> 1;
    const int q0w = q0 + w * 16;

    const int rowk = tid >> 4, posc = tid & 15;
    const int vrow = tid >> 3, vkb = tid & 7;
    const bf16* VTh = VT + (size_t)gh * 128 * 2048;

    bf16x8 qf[4];
    #pragma unroll
    for (int ks = 0; ks < 4; ks++)
        qf[ks] = *(const bf16x8*)(Q + ((size_t)(q0w + r) * NH + h) * HD + ks * 32 + g * 8);

    f32x4 acc[8] = {};
    float m_run = -1e30f, l_run = 0.f;
    const float scale = 0.08838834764831845f;

    {
        const int kv0 = c0 * 64;
        #pragma unroll
        for (int c = 0; c < 4; c++) {
            int row = c * 16 + rowk;
            int srcc = posc ^ (row & 7);
            gl_lds16(K + ((size_t)(kv0 + row) * NKV + gh) * HD + srcc * 8,
                     (char*)&Ks2[0][0] + c * 4096 + tid * 16);
        }
        asm volatile("s_waitcnt vmcnt(0)" ::: "memory");
        __builtin_amdgcn_s_barrier();
    }

    for (int t = 0; t < ntl; ++t) {
        const int b = t & 1;
        const int kv0 = (c0 + t) * 64;
        const bool pf = (t + 1 < ntl);
        #pragma unroll
        for (int it = 0; it < 4; it++) {
            int d = it * 32 + vrow;
            int srck = (vkb ^ (vrow & 7)) * 8;
            gl_lds16(VTh + (size_t)d * 2048 + kv0 + srck,
                     (char*)&Vt[0] + it * 4096 + tid * 16);
        }
        if (pf) {
            const int kv1 = kv0 + 64;
            #pragma unroll
            for (int c = 0; c < 4; c++) {
                int row = c * 16 + rowk;
                int srcc = posc ^ (row & 7);
                gl_lds16(K + ((size_t)(kv1 + row) * NKV + gh) * HD + srcc * 8,
                         (char*)&Ks2[0][0] + (b ^ 1) * 16384 + c * 4096 + tid * 16);
            }
        }
        const bool compute = (kv0 <= q0w + 15);
        union PB { uint32_t u[2]; short4v s; };
        PB pbu[4];
        if (compute) {
            const bf16* Kb = &Ks2[b][0];
            const bool fullt = (kv0 + 63 <= q0w);
            float sc[4][4];
            __builtin_amdgcn_s_setprio(1);
            #pragma unroll
            for (int t4 = 0; t4 < 4; t4++) {
                f32x4 S = {};
                #pragma unroll
                for (int ks = 0; ks < 4; ks++) {
                    int row = t4 * 16 + r;
                    bf16x8 kf = *(const bf16x8*)(Kb + row * 128 + (((4 * ks + g) ^ (row & 7)) * 8));
                    S = MFMA(kf, qf[ks], S);
                }
                if (fullt) {
                    #pragma unroll
                    for (int j = 0; j < 4; j++) sc[t4][j] = S[j] * scale;
                } else {
                    #pragma unroll
                    for (int j = 0; j < 4; j++) {
                        int kg = kv0 + t4 * 16 + 4 * g + j;
                        sc[t4][j] = (kg <= q0w + r) ? S[j] * scale : -1e30f;
                    }
                }
            }
            __builtin_amdgcn_s_setprio(0);
            float mx = sc[0][0];
            #pragma unroll
            for (int t4 = 0; t4 < 4; t4++)
                #pragma unroll
                for (int j = 0; j < 4; j++) mx = fmaxf(mx, sc[t4][j]);
            mx = fmaxf(mx, __shfl_xor(mx, 16));
            mx = fmaxf(mx, __shfl_xor(mx, 32));
            const bool nr = __all(mx <= m_run + 8.0f) != 0;
            float mn, alpha;
            if (nr) { mn = m_run; alpha = 1.0f; }
            else    { mn = fmaxf(m_run, mx); alpha = __expf(m_run - mn); m_run = mn; }
            float rsum = 0.f;
            #pragma unroll
            for (int t4 = 0; t4 < 4; t4++)
                #pragma unroll
                for (int j = 0; j < 4; j++) {
                    sc[t4][j] = __expf(sc[t4][j] - mn);
                    rsum += sc[t4][j];
                }
            rsum += __shfl_xor(rsum, 16);
            rsum += __shfl_xor(rsum, 32);
            l_run = l_run * alpha + rsum;
            if (!nr) {
                #pragma unroll
                for (int f = 0; f < 8; f++)
                    #pragma unroll
                    for (int j = 0; j < 4; j++) acc[f][j] *= alpha;
            }
            #pragma unroll
            for (int t4 = 0; t4 < 4; t4++) {
                pbu[t4].u[0] = pk2(sc[t4][0], sc[t4][1]);
                pbu[t4].u[1] = pk2(sc[t4][2], sc[t4][3]);
            }
        }
        if (pf) asm volatile("s_waitcnt vmcnt(4)" ::: "memory");
        else    asm volatile("s_waitcnt vmcnt(0)" ::: "memory");
        __builtin_amdgcn_s_barrier();
        if (compute) {
            const char* Vb = (const char*)&Vt[0];
            __builtin_amdgcn_s_setprio(1);
            #pragma unroll
            for (int f = 0; f < 8; f++) {
                #pragma unroll
                for (int t4 = 0; t4 < 4; t4++) {
                    short4v vf = *(const short4v*)(Vb + f * 2048 + r * 128 +
                                  (((2 * t4 + (g >> 1)) ^ (r & 7)) * 16) + (g & 1) * 8);
                    acc[f] = MFMA16(vf, pbu[t4].s, acc[f]);
                }
            }
            __builtin_amdgcn_s_setprio(0);
        }
        asm volatile("s_waitcnt vmcnt(0)" ::: "memory");
        __builtin_amdgcn_s_barrier();
    }
    const int lr = w * 16 + r;
    float inv_l = 1.0f / l_run;
    bf16* Ob = On + ((size_t)(h * 80 + y)) * 8192 + lr * 128;
    #pragma unroll
    for (int f = 0; f < 8; f++) {
        bf16x4v ov;
        #pragma unroll
        for (int j = 0; j < 4; j++) ov[j] = (bf16)(acc[f][j] * inv_l);
        *(bf16x4v*)(Ob + f * 16 + 4 * g) = ov;
    }
    if (g == 0) {
        float* mlp = ml + ((size_t)(h * 80 + y)) * 128;
        mlp[lr] = m_run;
        mlp[64 + lr] = l_run;
    }
}

// ---------------- combine partials (coalesced) ----------------
__global__ __launch_bounds__(256) void k_comb(const bf16* __restrict__ On,
                                              const float* __restrict__ ml,
                                              bf16* __restrict__ ao) {
    const int h = blockIdx.x, qt = blockIdx.y;
    const int tid = threadIdx.x;
    const int dc = tid & 15;
    const int qr = tid >> 4;
    const int nc = 1 + (qt >= 8) + (qt >= 16) + (qt >= 24);
    int ys[4];
    #pragma unroll
    for (int i = 0; i < 4; i++) ys[i] = (i < nc) ? yof(i, qt) : 0;
    #pragma unroll
    for (int p = 0; p < 4; p++) {
        const int lq = p * 16 + qr;
        float mi[4], li[4], wi[4];
        float mstar = -1e30f;
        for (int i = 0; i < 4; i++) {
            if (i < nc) {
                const float* pml = ml + ((size_t)(h * 80 + ys[i])) * 128;
                mi[i] = pml[lq]; li[i] = pml[64 + lq];
                mstar = fmaxf(mstar, mi[i]);
            }
        }
        float wsum = 0.f;
        for (int i = 0; i < 4; i++) {
            if (i < nc) { wi[i] = li[i] * __expf(mi[i] - mstar); wsum += wi[i]; }
            else wi[i] = 0.f;
        }
        float inv = 1.f / wsum;
        float o[8] = {};
        for (int i = 0; i < 4; i++) {
            if (i < nc) {
                bf16x8 v = *(const bf16x8*)(On + ((size_t)(h * 80 + ys[i])) * 8192 +
                                            lq * 128 + dc * 8);
                float wn = wi[i] * inv;
                #pragma unroll
                for (int j = 0; j < 8; j++) o[j] += wn * (float)v[j];
            }
        }
        bf16x8 ov;
        #pragma unroll
        for (int j = 0; j < 8; j++) ov[j] = (bf16)o[j];
        const int q = qt * 64 + lq;
        *(bf16x8*)(ao + ((size_t)q * NH + h) * HD + dc * 8) = ov;
    }
}

// ---------------- launch ----------------
extern "C" void kernel_launch(void* const* d_in, const int* in_sizes, int n_in,
                              void* d_out, int out_size, void* d_ws, size_t ws_size,
                              hipStream_t stream) {
    const int*   pos  = (const int*)d_in[0];
    const float* hid  = (const float*)d_in[1];
    const float* lw   = (const float*)d_in[2];
    const float* qkvw = (const float*)d_in[3];
    const float* qnw  = (const float*)d_in[4];
    const float* knw  = (const float*)d_in[5];
    const float* ow   = (const float*)d_in[6];
    float* out = (float*)d_out;

    char* ws = (char*)d_ws;
    bf16*   qkvw_b = (bf16*)(ws);                   // 0..16 MB
    bf16*   ow_b   = (bf16*)(ws + (16u << 20));     // 16..24 MB
    bf16*   normed = (bf16*)(ws + (24u << 20));     // 24..32 MB (reused as ao)
    bf16*   qkv3   = (bf16*)(ws + (32u << 20));     // 32..44.6 MB (dead after k_mid)
    bf16*   qb     = (bf16*)(ws + (64u << 20));     // 64..72 MB
    bf16*   kb     = (bf16*)(ws + (72u << 20));     // 72..76 MB
    bf16*   vb     = (bf16*)(ws + (76u << 20));     // 76..80 MB
    bf16*   ao     = normed;
    bf16*   On     = (bf16*)(ws + (32u << 20));     // reuses qkv3 region (21 MB)
    float*  ml     = (float*)(ws + (54u << 20));    // 54..54.7 MB
    bf16*   vT     = (bf16*)(ws + (56u << 20));     // 56..60 MB (transposed V)
    float2* rope   = (float2*)(ws + (60u << 20));   // 60..61 MB (RoPE table)

    k_pre<<<8704, 256, 0, stream>>>(qkvw, qkvw_b, ow, ow_b, hid, lw, normed, pos, rope);
    k_gemm_qkv<<<dim3(32, 16), 256, 0, stream>>>(normed, qkvw_b, qkv3, vb);
    k_mid<<<dim3(T_N, 13), 256, 0, stream>>>(qkv3, qnw, knw, rope, qb, kb, vb, vT);
    k_flash<<<dim3(NH, 80), 256, 0, stream>>>(qb, kb, vT, On, ml);
    k_comb<<<dim3(NH, 32), 256, 0, stream>>>(On, ml, ao);
    k_gemm_bt64<<<dim3(16, 32), 256, 0, stream>>>(ao, ow_b, out, 2048, 2048, 2048);
}